// Round 2
// 1471.996 us; speedup vs baseline: 1.0188x; 1.0188x over previous
//
#include <hip/hip_runtime.h>

typedef _Float16 f16;
typedef f16 f16x8 __attribute__((ext_vector_type(8)));
typedef float f32x4 __attribute__((ext_vector_type(4)));

#define BD 2048
#define SD 32
#define DD 1024
#define HD 1024
#define MD 4096
#define KD 32

// ---------- pack B (row-major [N,K] f32 source) into MFMA-frag-linear f16 hi(+lo) ----------
// frag order: [ntile][kc32][quad][l16][8 halfs] ; element = src[ntile*16+l16][kc32*32+quad*8+e]
__global__ void k_pack_rows(const float* __restrict__ in, f16* __restrict__ hi,
                            f16* __restrict__ lo, int N, int K) {
  int t = blockIdx.x * 256 + threadIdx.x;
  int total = (N >> 4) * (K >> 5) * 64;
  if (t >= total) return;
  int l16 = t & 15, quad = (t >> 4) & 3;
  int x = t >> 6;
  int kch = K >> 5;
  int kc = x % kch, nt = x / kch;
  const float* src = in + (size_t)(nt * 16 + l16) * K + kc * 32 + quad * 8;
  float4 u0 = *(const float4*)src;
  float4 u1 = *(const float4*)(src + 4);
  float v[8] = {u0.x, u0.y, u0.z, u0.w, u1.x, u1.y, u1.z, u1.w};
  f16x8 h, l;
#pragma unroll
  for (int e = 0; e < 8; ++e) {
    h[e] = (f16)v[e];
    l[e] = (f16)(v[e] - (float)h[e]);
  }
  ((f16x8*)hi)[t] = h;
  if (lo) ((f16x8*)lo)[t] = l;
}

// ---------- pack B = S^T where S is [K,N] f32 row-major ----------
__global__ void k_pack_T(const float* __restrict__ in, f16* __restrict__ hi,
                         f16* __restrict__ lo, int N, int K) {
  int t = blockIdx.x * 256 + threadIdx.x;
  int total = (N >> 4) * (K >> 5) * 64;
  if (t >= total) return;
  int l16 = t & 15, quad = (t >> 4) & 3;
  int x = t >> 6;
  int kch = K >> 5;
  int kc = x % kch, nt = x / kch;
  int col = nt * 16 + l16;          // B row index n
  int krow = kc * 32 + quad * 8;    // B col index k
  f16x8 h, l;
#pragma unroll
  for (int e = 0; e < 8; ++e) {
    float v = in[(size_t)(krow + e) * N + col];
    f16 hh = (f16)v;
    h[e] = hh;
    l[e] = (f16)(v - (float)hh);
  }
  ((f16x8*)hi)[t] = h;
  if (lo) ((f16x8*)lo)[t] = l;
}

__device__ __forceinline__ void cvt_split8(const float4& u0, const float4& u1,
                                           f16x8& h, f16x8& l) {
  float v[8] = {u0.x, u0.y, u0.z, u0.w, u1.x, u1.y, u1.z, u1.w};
#pragma unroll
  for (int e = 0; e < 8; ++e) {
    f16 hh = (f16)v[e];
    h[e] = hh;
    l[e] = (f16)(v[e] - (float)hh);
  }
}

// =====================================================================================
// k_gemm2: 256x128 block tile, BK=64, 512 thr = 8 waves (4M x 2N), wave tile 64x64.
// Double-buffered LDS for A only (two kc32 sub-tiles per buffer, each using the proven
// 0-conflict XOR-seg swizzle). B fragments read directly from frag-packed global
// (L2/L3-resident). One barrier per K-tile: issue next-tile global loads -> regs BEFORE
// the MFMA block (latency hides under compute), convert+ds_write to alt buffer AFTER.
// SPLIT=1: fp32 A split hi/lo in-kernel, 3-pass hh+hl+lh (same MFMA order & kc order as
// the 128^2 kernel -> bit-identical sim/topk). SPLIT=0: f16 A straight copy.
// XCD swizzle: xcd = blk%8; each XCD owns whole A-panels (mt = xcd + 8*p, nt fastest)
// so one panel is HBM-fetched once per XCD and L2-served for all its N-tiles.
// T5: s_setprio(1) around MFMA clusters (phase-split schedule -> scheduler has roles
// to arbitrate between load-issuing and MFMA-entering waves).
// EPI 0: C[row,col]=v   EPI 1: tanh+bias then mean over 32-row groups
// =====================================================================================
template <int SPLIT, int EPI>
__global__ __launch_bounds__(512, 2) void k_gemm2(const void* __restrict__ Ap,
                                                  const f16* __restrict__ Bhi,
                                                  const f16* __restrict__ Blo,
                                                  float* __restrict__ C,
                                                  const float* __restrict__ bias,
                                                  int M, int N, int K) {
  // [buf(2)][kc32(2)][row(256)][seg(4)*8 halfs] ; 64 KB (+64 KB lo when SPLIT)
  __shared__ f16 As[2 * 2 * 256 * 32];
  __shared__ f16 Asl[SPLIT ? 2 * 2 * 256 * 32 : 8];

  const int ntc = N >> 7;
  const int sblk = blockIdx.x;
  const int xcd = sblk & 7, q = sblk >> 3;
  const int nt = q % ntc;
  const int mt = xcd + ((q / ntc) << 3);
  const int m0 = mt << 8, n0 = nt << 7;

  const int t = threadIdx.x;
  const int lane = t & 63, w = t >> 6;
  const int wm = w >> 1, wn = w & 1;         // wm in [0,4) (M), wn in [0,2) (N)
  const int quad = lane >> 4, l16 = lane & 15;
  const int rwf = (l16 >> 1) & 3;            // read-side xor swizzle
  const int kch = K >> 5;
  const int NT = K >> 6;

  // staging decomposition: 4 reps cover [kc32(2)][row(256)][seg(4)] (8 elems each)
  int goff[4], sslot[4];
#pragma unroll
  for (int r = 0; r < 4; ++r) {
    int lin = r * 512 + t;
    int kc = lin >> 10;
    int row = (lin >> 2) & 255;
    int seg = lin & 3;
    goff[r] = (m0 + row) * K + kc * 32 + seg * 8;                 // element offset in A
    sslot[r] = kc * 8192 + row * 32 + ((seg ^ ((row >> 1) & 3)) << 3);
  }

  f32x4 acc[4][4] = {};

  // ---- prologue: stage K-tile 0 into buffer 0 ----
#pragma unroll
  for (int r = 0; r < 4; ++r) {
    if (SPLIT) {
      const float* g = (const float*)Ap + (size_t)goff[r];
      float4 u0 = *(const float4*)g;
      float4 u1 = *(const float4*)(g + 4);
      f16x8 h, l;
      cvt_split8(u0, u1, h, l);
      *(f16x8*)(As + sslot[r]) = h;
      *(f16x8*)(Asl + sslot[r]) = l;
    } else {
      const f16* g = (const f16*)Ap + (size_t)goff[r];
      *(f16x8*)(As + sslot[r]) = *(const f16x8*)g;
    }
  }
  __syncthreads();

  int cur = 0;
  for (int kt = 0; kt < NT; ++kt) {
    const bool pf = (kt + 1 < NT);
    // ---- (1) issue next K-tile global loads into regs (overlap with MFMA below) ----
    float4 nx0[4], nx1[4];
    f16x8 nxh[4];
    if (pf) {
#pragma unroll
      for (int r = 0; r < 4; ++r) {
        if (SPLIT) {
          const float* g = (const float*)Ap + (size_t)goff[r] + (size_t)(kt + 1) * 64;
          nx0[r] = *(const float4*)g;
          nx1[r] = *(const float4*)(g + 4);
        } else {
          const f16* g = (const f16*)Ap + (size_t)goff[r] + (size_t)(kt + 1) * 64;
          nxh[r] = *(const f16x8*)g;
        }
      }
    }
    // ---- (2) compute on buffer cur ----
    const f16* ba = As + cur * 16384;
    const f16* bal = Asl + (SPLIT ? cur * 16384 : 0);
#pragma unroll
    for (int kc = 0; kc < 2; ++kc) {
      const int kabs = kt * 2 + kc;
      f16x8 bh[4], bl[4];
#pragma unroll
      for (int j = 0; j < 4; ++j) {
        size_t fi = (((size_t)((n0 >> 4) + wn * 4 + j) * kch + kabs) << 6) + (quad << 4) + l16;
        bh[j] = ((const f16x8*)Bhi)[fi];
        if (SPLIT) bl[j] = ((const f16x8*)Blo)[fi];
      }
      f16x8 ah[4], al[4];
#pragma unroll
      for (int i = 0; i < 4; ++i) {
        int off = kc * 8192 + (wm * 64 + i * 16 + l16) * 32 + ((quad ^ rwf) << 3);
        ah[i] = *(const f16x8*)(ba + off);
        if (SPLIT) al[i] = *(const f16x8*)(bal + off);
      }
      __builtin_amdgcn_s_setprio(1);
      if (SPLIT) {
#pragma unroll
        for (int i = 0; i < 4; ++i)
#pragma unroll
          for (int j = 0; j < 4; ++j) {
            acc[i][j] = __builtin_amdgcn_mfma_f32_16x16x32_f16(ah[i], bh[j], acc[i][j], 0, 0, 0);
            acc[i][j] = __builtin_amdgcn_mfma_f32_16x16x32_f16(ah[i], bl[j], acc[i][j], 0, 0, 0);
            acc[i][j] = __builtin_amdgcn_mfma_f32_16x16x32_f16(al[i], bh[j], acc[i][j], 0, 0, 0);
          }
      } else {
#pragma unroll
        for (int i = 0; i < 4; ++i)
#pragma unroll
          for (int j = 0; j < 4; ++j)
            acc[i][j] = __builtin_amdgcn_mfma_f32_16x16x32_f16(ah[i], bh[j], acc[i][j], 0, 0, 0);
      }
      __builtin_amdgcn_s_setprio(0);
    }
    // ---- (3) convert + write next tile into alternate buffer ----
    if (pf) {
      f16* da = As + (cur ^ 1) * 16384;
      f16* dal = Asl + (SPLIT ? (cur ^ 1) * 16384 : 0);
#pragma unroll
      for (int r = 0; r < 4; ++r) {
        if (SPLIT) {
          f16x8 h, l;
          cvt_split8(nx0[r], nx1[r], h, l);
          *(f16x8*)(da + sslot[r]) = h;
          *(f16x8*)(dal + sslot[r]) = l;
        } else {
          *(f16x8*)(da + sslot[r]) = nxh[r];
        }
      }
    }
    __syncthreads();
    cur ^= 1;
  }

  if (EPI == 0) {
#pragma unroll
    for (int i = 0; i < 4; ++i) {
#pragma unroll
      for (int j = 0; j < 4; ++j) {
        int row = m0 + wm * 64 + i * 16 + quad * 4;
        int col = n0 + wn * 64 + j * 16 + l16;
        float* cp = C + (size_t)row * N + col;
#pragma unroll
        for (int r = 0; r < 4; ++r) cp[(size_t)r * N] = acc[i][j][r];
      }
    }
  } else {  // EPI == 1: tanh + bias, mean over 32-row groups
#pragma unroll
    for (int j = 0; j < 4; ++j) {
      int col = n0 + wn * 64 + j * 16 + l16;
      float bv = bias[col];
      float g0 = 0.f, g1 = 0.f;
#pragma unroll
      for (int i = 0; i < 4; ++i) {
        float s = 0.f;
#pragma unroll
        for (int r = 0; r < 4; ++r) s += tanhf(acc[i][j][r] + bv);
        if (i < 2) g0 += s; else g1 += s;
      }
      g0 += __shfl_xor(g0, 16); g0 += __shfl_xor(g0, 32);
      g1 += __shfl_xor(g1, 16); g1 += __shfl_xor(g1, 32);
      if (quad == 0) {
        int grp = (m0 + wm * 64) >> 5;
        C[(size_t)grp * N + col] = g0 * (1.0f / 32.0f);
        C[(size_t)(grp + 1) * N + col] = g1 * (1.0f / 32.0f);
      }
    }
  }
}

// ---------------- legacy 128x128 GEMM (kept for decode: EPI 3 broadcast epilogue) ------
template <int SPLIT, int EPI>
__global__ __launch_bounds__(256) void k_gemm(const void* __restrict__ Ap,
                                              const f16* __restrict__ Bhi,
                                              const f16* __restrict__ Blo,
                                              float* __restrict__ C,
                                              const float* __restrict__ bias,
                                              int M, int N, int K) {
  __shared__ f16 As[128 * 32];
  __shared__ f16 Asl[SPLIT ? 128 * 32 : 8];
  const int n0 = blockIdx.x * 128, m0 = blockIdx.y * 128;
  const int t = threadIdx.x;
  const int lane = t & 63, w = t >> 6;
  const int wm = w >> 1, wn = w & 1;
  const int quad = lane >> 4, l16 = lane & 15;
  const int srow = t >> 2, sseg = t & 3;
  const int swf = (srow >> 1) & 3;
  const int rwf = (l16 >> 1) & 3;
  const int kch = K >> 5;

  f32x4 acc[4][4] = {};

  for (int kc32 = 0; kc32 < kch; ++kc32) {
    const int kc = kc32 << 5;
    f16x8 bh[4], bl[4];
#pragma unroll
    for (int j = 0; j < 4; ++j) {
      size_t fi = (((size_t)((n0 >> 4) + wn * 4 + j) * kch + kc32) << 6) + (quad << 4) + l16;
      bh[j] = ((const f16x8*)Bhi)[fi];
      if (SPLIT) bl[j] = ((const f16x8*)Blo)[fi];
    }
#pragma unroll
    for (int rep = 0; rep < 2; ++rep) {
      int row = srow + rep * 64;
      int slot = row * 32 + ((sseg ^ swf) << 3);
      if (SPLIT) {
        const float* g = (const float*)Ap + (size_t)(m0 + row) * K + kc + sseg * 8;
        float4 u0 = *(const float4*)g;
        float4 u1 = *(const float4*)(g + 4);
        f16x8 h, l;
        cvt_split8(u0, u1, h, l);
        *(f16x8*)(As + slot) = h;
        *(f16x8*)(Asl + slot) = l;
      } else {
        const f16* g = (const f16*)Ap + (size_t)(m0 + row) * K + kc + sseg * 8;
        *(f16x8*)(As + slot) = *(const f16x8*)g;
      }
    }
    __syncthreads();
    f16x8 ah[4], al[4];
#pragma unroll
    for (int i = 0; i < 4; ++i) {
      int off = (wm * 64 + i * 16 + l16) * 32 + ((quad ^ rwf) << 3);
      ah[i] = *(const f16x8*)(As + off);
      if (SPLIT) al[i] = *(const f16x8*)(Asl + off);
    }
    if (SPLIT) {
#pragma unroll
      for (int i = 0; i < 4; ++i)
#pragma unroll
        for (int j = 0; j < 4; ++j) {
          acc[i][j] = __builtin_amdgcn_mfma_f32_16x16x32_f16(ah[i], bh[j], acc[i][j], 0, 0, 0);
          acc[i][j] = __builtin_amdgcn_mfma_f32_16x16x32_f16(ah[i], bl[j], acc[i][j], 0, 0, 0);
          acc[i][j] = __builtin_amdgcn_mfma_f32_16x16x32_f16(al[i], bh[j], acc[i][j], 0, 0, 0);
        }
    } else {
#pragma unroll
      for (int i = 0; i < 4; ++i)
#pragma unroll
        for (int j = 0; j < 4; ++j)
          acc[i][j] = __builtin_amdgcn_mfma_f32_16x16x32_f16(ah[i], bh[j], acc[i][j], 0, 0, 0);
    }
    __syncthreads();
  }

  if (EPI == 0) {
#pragma unroll
    for (int i = 0; i < 4; ++i) {
#pragma unroll
      for (int j = 0; j < 4; ++j) {
        int row = m0 + wm * 64 + i * 16 + quad * 4;
        int col = n0 + wn * 64 + j * 16 + l16;
        float* cp = C + (size_t)row * N + col;
#pragma unroll
        for (int r = 0; r < 4; ++r) cp[(size_t)r * N] = acc[i][j][r];
      }
    }
  } else if (EPI == 2) {
#pragma unroll
    for (int i = 0; i < 4; ++i) {
#pragma unroll
      for (int j = 0; j < 4; ++j) {
        int row = m0 + wm * 64 + i * 16 + quad * 4;
        int col = n0 + wn * 64 + j * 16 + l16;
        float bv = bias[col];
        float* cp = C + (size_t)row * N + col;
#pragma unroll
        for (int r = 0; r < 4; ++r) cp[(size_t)r * N] = tanhf(acc[i][j][r] + bv);
      }
    }
  } else if (EPI == 3) {  // tanh + bias + broadcast over SD
#pragma unroll
    for (int i = 0; i < 4; ++i) {
#pragma unroll
      for (int j = 0; j < 4; ++j) {
        int row = m0 + wm * 64 + i * 16 + quad * 4;
        int col = n0 + wn * 64 + j * 16 + l16;
        float bv = bias[col];
        float vv[4];
#pragma unroll
        for (int r = 0; r < 4; ++r) vv[r] = tanhf(acc[i][j][r] + bv);
        for (int s = 0; s < SD; ++s) {
          float* cp = C + ((size_t)row * SD + s) * N + col;
#pragma unroll
          for (int r = 0; r < 4; ++r) cp[(size_t)r * SD * N] = vv[r];
        }
      }
    }
  } else {  // EPI == 1
#pragma unroll
    for (int j = 0; j < 4; ++j) {
      int col = n0 + wn * 64 + j * 16 + l16;
      float bv = bias[col];
      float g0 = 0.f, g1 = 0.f;
#pragma unroll
      for (int i = 0; i < 4; ++i) {
        float s = 0.f;
#pragma unroll
        for (int r = 0; r < 4; ++r) s += tanhf(acc[i][j][r] + bv);
        if (i < 2) g0 += s; else g1 += s;
      }
      g0 += __shfl_xor(g0, 16); g0 += __shfl_xor(g0, 32);
      g1 += __shfl_xor(g1, 16); g1 += __shfl_xor(g1, 32);
      if (quad == 0) {
        int grp = (m0 + wm * 64) >> 5;
        C[(size_t)grp * N + col] = g0 * (1.0f / 32.0f);
        C[(size_t)(grp + 1) * N + col] = g1 * (1.0f / 32.0f);
      }
    }
  }
}

// ---------------- gate: scale[b] = (0.5 + sigmoid(q.w_curv + b_curv)) / max(temp,1e-6) --------
__global__ void k_gate(const float* __restrict__ query, const float* __restrict__ w_curv,
                       const float* __restrict__ b_curv, const float* __restrict__ temp,
                       float* __restrict__ scale) {
  int b = blockIdx.x, t = threadIdx.x;
  float s = 0.f;
  for (int h = t; h < HD; h += 256) s += query[(size_t)b * HD + h] * w_curv[h];
#pragma unroll
  for (int off = 32; off; off >>= 1) s += __shfl_xor(s, off);
  __shared__ float red[4];
  if ((t & 63) == 0) red[t >> 6] = s;
  __syncthreads();
  if (t == 0) {
    float tot = red[0] + red[1] + red[2] + red[3] + b_curv[0];
    float g = 1.f / (1.f + expf(-tot));
    scale[b] = (0.5f + g) / fmaxf(temp[0], 1e-6f);
  }
}

// ---------------- top-32 per row (iterative argmax in LDS) ----------------
__global__ void k_topk(const float* __restrict__ sim, const float* __restrict__ scale,
                       int* __restrict__ idx, float* __restrict__ vals) {
  int b = blockIdx.x, t = threadIdx.x;
  __shared__ float sv[MD];
  __shared__ float rv[4];
  __shared__ int ri[4];
  for (int i = t; i < MD; i += 256) sv[i] = sim[(size_t)b * MD + i];
  __syncthreads();
  float sc = scale[b];
  for (int k = 0; k < KD; ++k) {
    float bv = -1e30f;
    int bi = 0x7fffffff;
    for (int i = t; i < MD; i += 256) {
      float v = sv[i];
      if (v > bv) { bv = v; bi = i; }
    }
#pragma unroll
    for (int off = 1; off < 64; off <<= 1) {
      float ov = __shfl_xor(bv, off);
      int oi = __shfl_xor(bi, off);
      if (ov > bv || (ov == bv && oi < bi)) { bv = ov; bi = oi; }
    }
    if ((t & 63) == 0) { rv[t >> 6] = bv; ri[t >> 6] = bi; }
    __syncthreads();
    if (t == 0) {
      float fv = rv[0];
      int fi = ri[0];
#pragma unroll
      for (int u = 1; u < 4; ++u)
        if (rv[u] > fv || (rv[u] == fv && ri[u] < fi)) { fv = rv[u]; fi = ri[u]; }
      idx[b * KD + k] = fi;
      vals[b * KD + k] = fv * sc;
      sv[fi] = -1e30f;
    }
    __syncthreads();
  }
}

// ---------------- row softmax f32 -> f16 ----------------
__global__ void k_softmax(const float* __restrict__ in, f16* __restrict__ out, int C) {
  int b = blockIdx.x, t = threadIdx.x;
  const float* row = in + (size_t)b * C;
  __shared__ float red[4];
  float m = -1e30f;
  for (int i = t; i < C; i += 256) m = fmaxf(m, row[i]);
#pragma unroll
  for (int off = 32; off; off >>= 1) m = fmaxf(m, __shfl_xor(m, off));
  if ((t & 63) == 0) red[t >> 6] = m;
  __syncthreads();
  m = fmaxf(fmaxf(red[0], red[1]), fmaxf(red[2], red[3]));
  __syncthreads();
  float s = 0.f;
  for (int i = t; i < C; i += 256) s += expf(row[i] - m);
#pragma unroll
  for (int off = 32; off; off >>= 1) s += __shfl_xor(s, off);
  if ((t & 63) == 0) red[t >> 6] = s;
  __syncthreads();
  s = red[0] + red[1] + red[2] + red[3];
  float inv = 1.f / s;
  for (int i = t; i < C; i += 256) out[(size_t)b * C + i] = (f16)(expf(row[i] - m) * inv);
}

// ---------------- combine: softmax(vals + act[idx]) weighted gather of memory_slots --------
__global__ void k_combine(const float* __restrict__ vals, const int* __restrict__ idx,
                          const float* __restrict__ act, const float* __restrict__ mem,
                          f16* __restrict__ read_h) {
  int b = blockIdx.x, t = threadIdx.x;
  __shared__ float comb[KD];
  __shared__ int sidx[KD];
  if (t < KD) {
    int id = idx[b * KD + t];
    sidx[t] = id;
    float e = vals[b * KD + t] + act[(size_t)b * MD + id];
    float m = e;
#pragma unroll
    for (int off = 16; off; off >>= 1) m = fmaxf(m, __shfl_xor(m, off));
    float p = expf(e - m);
    float s = p;
#pragma unroll
    for (int off = 16; off; off >>= 1) s += __shfl_xor(s, off);
    comb[t] = p / s;
  }
  __syncthreads();
  for (int h = t; h < HD; h += 256) {
    float a = 0.f;
#pragma unroll
    for (int k = 0; k < KD; ++k) a += comb[k] * mem[(size_t)sidx[k] * HD + h];
    read_h[(size_t)b * HD + h] = (f16)a;
  }
}

extern "C" void kernel_launch(void* const* d_in, const int* in_sizes, int n_in,
                              void* d_out, int out_size, void* d_ws, size_t ws_size,
                              hipStream_t stream) {
  const float* x      = (const float*)d_in[0];
  const float* W_enc  = (const float*)d_in[2];
  const float* b_enc  = (const float*)d_in[3];
  const float* w_curv = (const float*)d_in[4];
  const float* b_curv = (const float*)d_in[5];
  const float* mem    = (const float*)d_in[6];
  const float* assoc  = (const float*)d_in[7];
  const float* W_dec  = (const float*)d_in[8];
  const float* b_dec  = (const float*)d_in[9];
  const float* temp   = (const float*)d_in[10];
  float* out = (float*)d_out;

  char* ws = (char*)d_ws;
  size_t off = 0;
  auto alloc = [&](size_t bytes) {
    void* p = ws + off;
    off += (bytes + 255) & ~(size_t)255;
    return p;
  };
  f16* Wt_hi   = (f16*)alloc((size_t)HD * DD * 2);   // W_enc^T frag-packed hi
  f16* Wt_lo   = (f16*)alloc((size_t)HD * DD * 2);
  f16* ms_hi   = (f16*)alloc((size_t)MD * HD * 2);   // memory_slots frag-packed hi
  f16* ms_lo   = (f16*)alloc((size_t)MD * HD * 2);
  f16* as_pk   = (f16*)alloc((size_t)MD * MD * 2);   // assoc^T frag-packed
  f16* wd_pk   = (f16*)alloc((size_t)HD * DD * 2);   // W_dec^T frag-packed
  float* query = (float*)alloc((size_t)BD * HD * 4);
  float* scale = (float*)alloc((size_t)BD * 4);
  float* sim   = (float*)alloc((size_t)BD * MD * 4); // reused as act1/act2
  int* idx     = (int*)alloc((size_t)BD * KD * 4);
  float* vals  = (float*)alloc((size_t)BD * KD * 4);
  f16* p_h     = (f16*)alloc((size_t)BD * MD * 2);
  f16* read_h  = (f16*)alloc((size_t)BD * HD * 2);
  (void)ws_size; (void)in_sizes; (void)n_in; (void)out_size;

  dim3 b256(256), b512(512);
  // ---- operand frag-packing ----
  k_pack_T<<<dim3((HD / 16) * (DD / 32) * 64 / 256), b256, 0, stream>>>(W_enc, Wt_hi, Wt_lo, HD, DD);
  k_pack_rows<<<dim3((MD / 16) * (HD / 32) * 64 / 256), b256, 0, stream>>>(mem, ms_hi, ms_lo, MD, HD);
  k_pack_T<<<dim3((MD / 16) * (MD / 32) * 64 / 256), b256, 0, stream>>>(assoc, as_pk, nullptr, MD, MD);
  k_pack_T<<<dim3((DD / 16) * (HD / 32) * 64 / 256), b256, 0, stream>>>(W_dec, wd_pk, nullptr, DD, HD);
  // ---- enc GEMM (split-3, pipelined 256x128) + tanh + mean_s -> query [B,H] ----
  k_gemm2<1, 1><<<dim3((BD * SD / 256) * (HD / 128)), b512, 0, stream>>>(
      x, Wt_hi, Wt_lo, query, b_enc, BD * SD, HD, DD);
  // ---- gate scale per row ----
  k_gate<<<dim3(BD), b256, 0, stream>>>(query, w_curv, b_curv, temp, scale);
  // ---- sim = query @ memory_slots^T (split-3, pipelined) ----
  k_gemm2<1, 0><<<dim3((BD / 256) * (MD / 128)), b512, 0, stream>>>(
      query, ms_hi, ms_lo, sim, nullptr, BD, MD, HD);
  // ---- top-32 ----
  k_topk<<<dim3(BD), b256, 0, stream>>>(sim, scale, idx, vals);
  // ---- two rounds: softmax -> @ assoc ----
  k_softmax<<<dim3(BD), b256, 0, stream>>>(sim, p_h, MD);
  k_gemm2<0, 0><<<dim3((BD / 256) * (MD / 128)), b512, 0, stream>>>(
      p_h, as_pk, nullptr, sim, nullptr, BD, MD, MD);
  k_softmax<<<dim3(BD), b256, 0, stream>>>(sim, p_h, MD);
  k_gemm2<0, 0><<<dim3((BD / 256) * (MD / 128)), b512, 0, stream>>>(
      p_h, as_pk, nullptr, sim, nullptr, BD, MD, MD);
  // ---- combine softmax + weighted gather -> read [B,H] f16 ----
  k_combine<<<dim3(BD), b256, 0, stream>>>(vals, idx, sim, mem, read_h);
  // ---- decode GEMM + tanh + fused broadcast over S -> out [B,S,D] (write-bound; keep 128^2) ----
  k_gemm<0, 3><<<dim3(DD / 128, BD / 128), b256, 0, stream>>>(
      read_h, wd_pk, nullptr, out, b_dec, BD, DD, HD);
}

// Round 3
// 1469.279 us; speedup vs baseline: 1.0206x; 1.0018x over previous
//
#include <hip/hip_runtime.h>

typedef _Float16 f16;
typedef f16 f16x8 __attribute__((ext_vector_type(8)));
typedef float f32x4 __attribute__((ext_vector_type(4)));

#define BD 2048
#define SD 32
#define DD 1024
#define HD 1024
#define MD 4096
#define KD 32

// ---------- pack B (row-major [N,K] f32 source) into MFMA-frag-linear f16 hi(+lo) ----------
// frag order: [ntile][kc32][quad][l16][8 halfs] ; element = src[ntile*16+l16][kc32*32+quad*8+e]
__global__ void k_pack_rows(const float* __restrict__ in, f16* __restrict__ hi,
                            f16* __restrict__ lo, int N, int K) {
  int t = blockIdx.x * 256 + threadIdx.x;
  int total = (N >> 4) * (K >> 5) * 64;
  if (t >= total) return;
  int l16 = t & 15, quad = (t >> 4) & 3;
  int x = t >> 6;
  int kch = K >> 5;
  int kc = x % kch, nt = x / kch;
  const float* src = in + (size_t)(nt * 16 + l16) * K + kc * 32 + quad * 8;
  float4 u0 = *(const float4*)src;
  float4 u1 = *(const float4*)(src + 4);
  float v[8] = {u0.x, u0.y, u0.z, u0.w, u1.x, u1.y, u1.z, u1.w};
  f16x8 h, l;
#pragma unroll
  for (int e = 0; e < 8; ++e) {
    h[e] = (f16)v[e];
    l[e] = (f16)(v[e] - (float)h[e]);
  }
  ((f16x8*)hi)[t] = h;
  if (lo) ((f16x8*)lo)[t] = l;
}

// ---------- pack B = S^T where S is [K,N] f32 row-major ----------
__global__ void k_pack_T(const float* __restrict__ in, f16* __restrict__ hi,
                         f16* __restrict__ lo, int N, int K) {
  int t = blockIdx.x * 256 + threadIdx.x;
  int total = (N >> 4) * (K >> 5) * 64;
  if (t >= total) return;
  int l16 = t & 15, quad = (t >> 4) & 3;
  int x = t >> 6;
  int kch = K >> 5;
  int kc = x % kch, nt = x / kch;
  int col = nt * 16 + l16;          // B row index n
  int krow = kc * 32 + quad * 8;    // B col index k
  f16x8 h, l;
#pragma unroll
  for (int e = 0; e < 8; ++e) {
    float v = in[(size_t)(krow + e) * N + col];
    f16 hh = (f16)v;
    h[e] = hh;
    l[e] = (f16)(v - (float)hh);
  }
  ((f16x8*)hi)[t] = h;
  if (lo) ((f16x8*)lo)[t] = l;
}

__device__ __forceinline__ void cvt_split8(const float4& u0, const float4& u1,
                                           f16x8& h, f16x8& l) {
  float v[8] = {u0.x, u0.y, u0.z, u0.w, u1.x, u1.y, u1.z, u1.w};
#pragma unroll
  for (int e = 0; e < 8; ++e) {
    f16 hh = (f16)v[e];
    h[e] = hh;
    l[e] = (f16)(v[e] - (float)hh);
  }
}

// =====================================================================================
// k_gemm2: 256x128 block tile, BK=64, 512 thr = 8 waves (4M x 2N), wave tile 64x64.
// Double-buffered LDS for A only (two kc32 sub-tiles per buffer, each using the proven
// 0-conflict XOR-seg swizzle). B fragments read directly from frag-packed global
// (L2/L3-resident). One barrier per K-tile: issue next-tile global loads -> regs BEFORE
// the MFMA block (latency hides under compute), convert+ds_write to alt buffer AFTER.
// SPLIT=1: fp32 A split hi/lo in-kernel, 3-pass hh+hl+lh (same MFMA order & kc order as
// the 128^2 kernel -> bit-identical sim/topk). SPLIT=0: f16 A straight copy.
// XCD swizzle: xcd = blk%8; each XCD owns whole A-panels (mt = xcd + 8*p, nt fastest).
// waves_per_eu(2,2): LDS (128 KB) caps residency at 1 block/CU = 2 waves/SIMD no matter
// what, so pin the compiler's occupancy assumption there -> VGPR budget ~256 -> the
// prefetched next-tile registers stay live across the MFMA cluster (round-2's VGPR=108
// allocation sank the prefetch loads to their use, de-pipelining the loop).
// EPI 0: C[row,col]=v   EPI 1: tanh+bias then mean over 32-row groups
// =====================================================================================
template <int SPLIT, int EPI>
__global__ __attribute__((amdgpu_flat_work_group_size(512, 512)))
__attribute__((amdgpu_waves_per_eu(2, 2)))
void k_gemm2(const void* __restrict__ Ap,
             const f16* __restrict__ Bhi,
             const f16* __restrict__ Blo,
             float* __restrict__ C,
             const float* __restrict__ bias,
             int M, int N, int K) {
  // [buf(2)][kc32(2)][row(256)][seg(4)*8 halfs] ; 64 KB (+64 KB lo when SPLIT)
  __shared__ f16 As[2 * 2 * 256 * 32];
  __shared__ f16 Asl[SPLIT ? 2 * 2 * 256 * 32 : 8];

  const int ntc = N >> 7;
  const int sblk = blockIdx.x;
  const int xcd = sblk & 7, q = sblk >> 3;
  const int nt = q % ntc;
  const int mt = xcd + ((q / ntc) << 3);
  const int m0 = mt << 8, n0 = nt << 7;

  const int t = threadIdx.x;
  const int lane = t & 63, w = t >> 6;
  const int wm = w >> 1, wn = w & 1;         // wm in [0,4) (M), wn in [0,2) (N)
  const int quad = lane >> 4, l16 = lane & 15;
  const int rwf = (l16 >> 1) & 3;            // read-side xor swizzle
  const int kch = K >> 5;
  const int NT = K >> 6;

  // staging decomposition: 4 reps cover [kc32(2)][row(256)][seg(4)] (8 elems each)
  int goff[4], sslot[4];
#pragma unroll
  for (int r = 0; r < 4; ++r) {
    int lin = r * 512 + t;
    int kc = lin >> 10;
    int row = (lin >> 2) & 255;
    int seg = lin & 3;
    goff[r] = (m0 + row) * K + kc * 32 + seg * 8;                 // element offset in A
    sslot[r] = kc * 8192 + row * 32 + ((seg ^ ((row >> 1) & 3)) << 3);
  }

  f32x4 acc[4][4] = {};

  // ---- prologue: stage K-tile 0 into buffer 0 ----
#pragma unroll
  for (int r = 0; r < 4; ++r) {
    if (SPLIT) {
      const float* g = (const float*)Ap + (size_t)goff[r];
      float4 u0 = *(const float4*)g;
      float4 u1 = *(const float4*)(g + 4);
      f16x8 h, l;
      cvt_split8(u0, u1, h, l);
      *(f16x8*)(As + sslot[r]) = h;
      *(f16x8*)(Asl + sslot[r]) = l;
    } else {
      const f16* g = (const f16*)Ap + (size_t)goff[r];
      *(f16x8*)(As + sslot[r]) = *(const f16x8*)g;
    }
  }
  __syncthreads();

  int cur = 0;
  for (int kt = 0; kt < NT; ++kt) {
    const bool pf = (kt + 1 < NT);
    // ---- (1) issue next K-tile global loads into regs (overlap with MFMA below) ----
    float4 nx0[4], nx1[4];
    f16x8 nxh[4];
    if (pf) {
#pragma unroll
      for (int r = 0; r < 4; ++r) {
        if (SPLIT) {
          const float* g = (const float*)Ap + (size_t)goff[r] + (size_t)(kt + 1) * 64;
          nx0[r] = *(const float4*)g;
          nx1[r] = *(const float4*)(g + 4);
        } else {
          const f16* g = (const f16*)Ap + (size_t)goff[r] + (size_t)(kt + 1) * 64;
          nxh[r] = *(const f16x8*)g;
        }
      }
    }
    // ---- (2) compute on buffer cur ----
    const f16* ba = As + cur * 16384;
    const f16* bal = Asl + (SPLIT ? cur * 16384 : 0);
#pragma unroll
    for (int kc = 0; kc < 2; ++kc) {
      const int kabs = kt * 2 + kc;
      f16x8 bh[4], bl[4];
#pragma unroll
      for (int j = 0; j < 4; ++j) {
        size_t fi = (((size_t)((n0 >> 4) + wn * 4 + j) * kch + kabs) << 6) + (quad << 4) + l16;
        bh[j] = ((const f16x8*)Bhi)[fi];
        if (SPLIT) bl[j] = ((const f16x8*)Blo)[fi];
      }
      f16x8 ah[4], al[4];
#pragma unroll
      for (int i = 0; i < 4; ++i) {
        int off = kc * 8192 + (wm * 64 + i * 16 + l16) * 32 + ((quad ^ rwf) << 3);
        ah[i] = *(const f16x8*)(ba + off);
        if (SPLIT) al[i] = *(const f16x8*)(bal + off);
      }
      __builtin_amdgcn_s_setprio(1);
      if (SPLIT) {
#pragma unroll
        for (int i = 0; i < 4; ++i)
#pragma unroll
          for (int j = 0; j < 4; ++j) {
            acc[i][j] = __builtin_amdgcn_mfma_f32_16x16x32_f16(ah[i], bh[j], acc[i][j], 0, 0, 0);
            acc[i][j] = __builtin_amdgcn_mfma_f32_16x16x32_f16(ah[i], bl[j], acc[i][j], 0, 0, 0);
            acc[i][j] = __builtin_amdgcn_mfma_f32_16x16x32_f16(al[i], bh[j], acc[i][j], 0, 0, 0);
          }
      } else {
#pragma unroll
        for (int i = 0; i < 4; ++i)
#pragma unroll
          for (int j = 0; j < 4; ++j)
            acc[i][j] = __builtin_amdgcn_mfma_f32_16x16x32_f16(ah[i], bh[j], acc[i][j], 0, 0, 0);
      }
      __builtin_amdgcn_s_setprio(0);
    }
    // ---- (3) convert + write next tile into alternate buffer ----
    if (pf) {
      f16* da = As + (cur ^ 1) * 16384;
      f16* dal = Asl + (SPLIT ? (cur ^ 1) * 16384 : 0);
#pragma unroll
      for (int r = 0; r < 4; ++r) {
        if (SPLIT) {
          f16x8 h, l;
          cvt_split8(nx0[r], nx1[r], h, l);
          *(f16x8*)(da + sslot[r]) = h;
          *(f16x8*)(dal + sslot[r]) = l;
        } else {
          *(f16x8*)(da + sslot[r]) = nxh[r];
        }
      }
    }
    __syncthreads();
    cur ^= 1;
  }

  if (EPI == 0) {
#pragma unroll
    for (int i = 0; i < 4; ++i) {
#pragma unroll
      for (int j = 0; j < 4; ++j) {
        int row = m0 + wm * 64 + i * 16 + quad * 4;
        int col = n0 + wn * 64 + j * 16 + l16;
        float* cp = C + (size_t)row * N + col;
#pragma unroll
        for (int r = 0; r < 4; ++r) cp[(size_t)r * N] = acc[i][j][r];
      }
    }
  } else {  // EPI == 1: tanh + bias, mean over 32-row groups
#pragma unroll
    for (int j = 0; j < 4; ++j) {
      int col = n0 + wn * 64 + j * 16 + l16;
      float bv = bias[col];
      float g0 = 0.f, g1 = 0.f;
#pragma unroll
      for (int i = 0; i < 4; ++i) {
        float s = 0.f;
#pragma unroll
        for (int r = 0; r < 4; ++r) s += tanhf(acc[i][j][r] + bv);
        if (i < 2) g0 += s; else g1 += s;
      }
      g0 += __shfl_xor(g0, 16); g0 += __shfl_xor(g0, 32);
      g1 += __shfl_xor(g1, 16); g1 += __shfl_xor(g1, 32);
      if (quad == 0) {
        int grp = (m0 + wm * 64) >> 5;
        C[(size_t)grp * N + col] = g0 * (1.0f / 32.0f);
        C[(size_t)(grp + 1) * N + col] = g1 * (1.0f / 32.0f);
      }
    }
  }
}

// ---------------- legacy 128x128 GEMM (kept for decode: EPI 3 broadcast epilogue) ------
template <int SPLIT, int EPI>
__global__ __launch_bounds__(256) void k_gemm(const void* __restrict__ Ap,
                                              const f16* __restrict__ Bhi,
                                              const f16* __restrict__ Blo,
                                              float* __restrict__ C,
                                              const float* __restrict__ bias,
                                              int M, int N, int K) {
  __shared__ f16 As[128 * 32];
  __shared__ f16 Asl[SPLIT ? 128 * 32 : 8];
  const int n0 = blockIdx.x * 128, m0 = blockIdx.y * 128;
  const int t = threadIdx.x;
  const int lane = t & 63, w = t >> 6;
  const int wm = w >> 1, wn = w & 1;
  const int quad = lane >> 4, l16 = lane & 15;
  const int srow = t >> 2, sseg = t & 3;
  const int swf = (srow >> 1) & 3;
  const int rwf = (l16 >> 1) & 3;
  const int kch = K >> 5;

  f32x4 acc[4][4] = {};

  for (int kc32 = 0; kc32 < kch; ++kc32) {
    const int kc = kc32 << 5;
    f16x8 bh[4], bl[4];
#pragma unroll
    for (int j = 0; j < 4; ++j) {
      size_t fi = (((size_t)((n0 >> 4) + wn * 4 + j) * kch + kc32) << 6) + (quad << 4) + l16;
      bh[j] = ((const f16x8*)Bhi)[fi];
      if (SPLIT) bl[j] = ((const f16x8*)Blo)[fi];
    }
#pragma unroll
    for (int rep = 0; rep < 2; ++rep) {
      int row = srow + rep * 64;
      int slot = row * 32 + ((sseg ^ swf) << 3);
      if (SPLIT) {
        const float* g = (const float*)Ap + (size_t)(m0 + row) * K + kc + sseg * 8;
        float4 u0 = *(const float4*)g;
        float4 u1 = *(const float4*)(g + 4);
        f16x8 h, l;
        cvt_split8(u0, u1, h, l);
        *(f16x8*)(As + slot) = h;
        *(f16x8*)(Asl + slot) = l;
      } else {
        const f16* g = (const f16*)Ap + (size_t)(m0 + row) * K + kc + sseg * 8;
        *(f16x8*)(As + slot) = *(const f16x8*)g;
      }
    }
    __syncthreads();
    f16x8 ah[4], al[4];
#pragma unroll
    for (int i = 0; i < 4; ++i) {
      int off = (wm * 64 + i * 16 + l16) * 32 + ((quad ^ rwf) << 3);
      ah[i] = *(const f16x8*)(As + off);
      if (SPLIT) al[i] = *(const f16x8*)(Asl + off);
    }
    if (SPLIT) {
#pragma unroll
      for (int i = 0; i < 4; ++i)
#pragma unroll
        for (int j = 0; j < 4; ++j) {
          acc[i][j] = __builtin_amdgcn_mfma_f32_16x16x32_f16(ah[i], bh[j], acc[i][j], 0, 0, 0);
          acc[i][j] = __builtin_amdgcn_mfma_f32_16x16x32_f16(ah[i], bl[j], acc[i][j], 0, 0, 0);
          acc[i][j] = __builtin_amdgcn_mfma_f32_16x16x32_f16(al[i], bh[j], acc[i][j], 0, 0, 0);
        }
    } else {
#pragma unroll
      for (int i = 0; i < 4; ++i)
#pragma unroll
        for (int j = 0; j < 4; ++j)
          acc[i][j] = __builtin_amdgcn_mfma_f32_16x16x32_f16(ah[i], bh[j], acc[i][j], 0, 0, 0);
    }
    __syncthreads();
  }

  if (EPI == 0) {
#pragma unroll
    for (int i = 0; i < 4; ++i) {
#pragma unroll
      for (int j = 0; j < 4; ++j) {
        int row = m0 + wm * 64 + i * 16 + quad * 4;
        int col = n0 + wn * 64 + j * 16 + l16;
        float* cp = C + (size_t)row * N + col;
#pragma unroll
        for (int r = 0; r < 4; ++r) cp[(size_t)r * N] = acc[i][j][r];
      }
    }
  } else if (EPI == 2) {
#pragma unroll
    for (int i = 0; i < 4; ++i) {
#pragma unroll
      for (int j = 0; j < 4; ++j) {
        int row = m0 + wm * 64 + i * 16 + quad * 4;
        int col = n0 + wn * 64 + j * 16 + l16;
        float bv = bias[col];
        float* cp = C + (size_t)row * N + col;
#pragma unroll
        for (int r = 0; r < 4; ++r) cp[(size_t)r * N] = tanhf(acc[i][j][r] + bv);
      }
    }
  } else if (EPI == 3) {  // tanh + bias + broadcast over SD
#pragma unroll
    for (int i = 0; i < 4; ++i) {
#pragma unroll
      for (int j = 0; j < 4; ++j) {
        int row = m0 + wm * 64 + i * 16 + quad * 4;
        int col = n0 + wn * 64 + j * 16 + l16;
        float bv = bias[col];
        float vv[4];
#pragma unroll
        for (int r = 0; r < 4; ++r) vv[r] = tanhf(acc[i][j][r] + bv);
        for (int s = 0; s < SD; ++s) {
          float* cp = C + ((size_t)row * SD + s) * N + col;
#pragma unroll
          for (int r = 0; r < 4; ++r) cp[(size_t)r * SD * N] = vv[r];
        }
      }
    }
  } else {  // EPI == 1
#pragma unroll
    for (int j = 0; j < 4; ++j) {
      int col = n0 + wn * 64 + j * 16 + l16;
      float bv = bias[col];
      float g0 = 0.f, g1 = 0.f;
#pragma unroll
      for (int i = 0; i < 4; ++i) {
        float s = 0.f;
#pragma unroll
        for (int r = 0; r < 4; ++r) s += tanhf(acc[i][j][r] + bv);
        if (i < 2) g0 += s; else g1 += s;
      }
      g0 += __shfl_xor(g0, 16); g0 += __shfl_xor(g0, 32);
      g1 += __shfl_xor(g1, 16); g1 += __shfl_xor(g1, 32);
      if (quad == 0) {
        int grp = (m0 + wm * 64) >> 5;
        C[(size_t)grp * N + col] = g0 * (1.0f / 32.0f);
        C[(size_t)(grp + 1) * N + col] = g1 * (1.0f / 32.0f);
      }
    }
  }
}

// ---------------- gate: scale[b] = (0.5 + sigmoid(q.w_curv + b_curv)) / max(temp,1e-6) --------
__global__ void k_gate(const float* __restrict__ query, const float* __restrict__ w_curv,
                       const float* __restrict__ b_curv, const float* __restrict__ temp,
                       float* __restrict__ scale) {
  int b = blockIdx.x, t = threadIdx.x;
  float s = 0.f;
  for (int h = t; h < HD; h += 256) s += query[(size_t)b * HD + h] * w_curv[h];
#pragma unroll
  for (int off = 32; off; off >>= 1) s += __shfl_xor(s, off);
  __shared__ float red[4];
  if ((t & 63) == 0) red[t >> 6] = s;
  __syncthreads();
  if (t == 0) {
    float tot = red[0] + red[1] + red[2] + red[3] + b_curv[0];
    float g = 1.f / (1.f + expf(-tot));
    scale[b] = (0.5f + g) / fmaxf(temp[0], 1e-6f);
  }
}

// ---------------- top-32 per row (iterative argmax in LDS) ----------------
__global__ void k_topk(const float* __restrict__ sim, const float* __restrict__ scale,
                       int* __restrict__ idx, float* __restrict__ vals) {
  int b = blockIdx.x, t = threadIdx.x;
  __shared__ float sv[MD];
  __shared__ float rv[4];
  __shared__ int ri[4];
  for (int i = t; i < MD; i += 256) sv[i] = sim[(size_t)b * MD + i];
  __syncthreads();
  float sc = scale[b];
  for (int k = 0; k < KD; ++k) {
    float bv = -1e30f;
    int bi = 0x7fffffff;
    for (int i = t; i < MD; i += 256) {
      float v = sv[i];
      if (v > bv) { bv = v; bi = i; }
    }
#pragma unroll
    for (int off = 1; off < 64; off <<= 1) {
      float ov = __shfl_xor(bv, off);
      int oi = __shfl_xor(bi, off);
      if (ov > bv || (ov == bv && oi < bi)) { bv = ov; bi = oi; }
    }
    if ((t & 63) == 0) { rv[t >> 6] = bv; ri[t >> 6] = bi; }
    __syncthreads();
    if (t == 0) {
      float fv = rv[0];
      int fi = ri[0];
#pragma unroll
      for (int u = 1; u < 4; ++u)
        if (rv[u] > fv || (rv[u] == fv && ri[u] < fi)) { fv = rv[u]; fi = ri[u]; }
      idx[b * KD + k] = fi;
      vals[b * KD + k] = fv * sc;
      sv[fi] = -1e30f;
    }
    __syncthreads();
  }
}

// ---------------- row softmax f32 -> f16 ----------------
__global__ void k_softmax(const float* __restrict__ in, f16* __restrict__ out, int C) {
  int b = blockIdx.x, t = threadIdx.x;
  const float* row = in + (size_t)b * C;
  __shared__ float red[4];
  float m = -1e30f;
  for (int i = t; i < C; i += 256) m = fmaxf(m, row[i]);
#pragma unroll
  for (int off = 32; off; off >>= 1) m = fmaxf(m, __shfl_xor(m, off));
  if ((t & 63) == 0) red[t >> 6] = m;
  __syncthreads();
  m = fmaxf(fmaxf(red[0], red[1]), fmaxf(red[2], red[3]));
  __syncthreads();
  float s = 0.f;
  for (int i = t; i < C; i += 256) s += expf(row[i] - m);
#pragma unroll
  for (int off = 32; off; off >>= 1) s += __shfl_xor(s, off);
  if ((t & 63) == 0) red[t >> 6] = s;
  __syncthreads();
  s = red[0] + red[1] + red[2] + red[3];
  float inv = 1.f / s;
  for (int i = t; i < C; i += 256) out[(size_t)b * C + i] = (f16)(expf(row[i] - m) * inv);
}

// ---------------- combine: softmax(vals + act[idx]) weighted gather of memory_slots --------
__global__ void k_combine(const float* __restrict__ vals, const int* __restrict__ idx,
                          const float* __restrict__ act, const float* __restrict__ mem,
                          f16* __restrict__ read_h) {
  int b = blockIdx.x, t = threadIdx.x;
  __shared__ float comb[KD];
  __shared__ int sidx[KD];
  if (t < KD) {
    int id = idx[b * KD + t];
    sidx[t] = id;
    float e = vals[b * KD + t] + act[(size_t)b * MD + id];
    float m = e;
#pragma unroll
    for (int off = 16; off; off >>= 1) m = fmaxf(m, __shfl_xor(m, off));
    float p = expf(e - m);
    float s = p;
#pragma unroll
    for (int off = 16; off; off >>= 1) s += __shfl_xor(s, off);
    comb[t] = p / s;
  }
  __syncthreads();
  for (int h = t; h < HD; h += 256) {
    float a = 0.f;
#pragma unroll
    for (int k = 0; k < KD; ++k) a += comb[k] * mem[(size_t)sidx[k] * HD + h];
    read_h[(size_t)b * HD + h] = (f16)a;
  }
}

extern "C" void kernel_launch(void* const* d_in, const int* in_sizes, int n_in,
                              void* d_out, int out_size, void* d_ws, size_t ws_size,
                              hipStream_t stream) {
  const float* x      = (const float*)d_in[0];
  const float* W_enc  = (const float*)d_in[2];
  const float* b_enc  = (const float*)d_in[3];
  const float* w_curv = (const float*)d_in[4];
  const float* b_curv = (const float*)d_in[5];
  const float* mem    = (const float*)d_in[6];
  const float* assoc  = (const float*)d_in[7];
  const float* W_dec  = (const float*)d_in[8];
  const float* b_dec  = (const float*)d_in[9];
  const float* temp   = (const float*)d_in[10];
  float* out = (float*)d_out;

  char* ws = (char*)d_ws;
  size_t off = 0;
  auto alloc = [&](size_t bytes) {
    void* p = ws + off;
    off += (bytes + 255) & ~(size_t)255;
    return p;
  };
  f16* Wt_hi   = (f16*)alloc((size_t)HD * DD * 2);   // W_enc^T frag-packed hi
  f16* Wt_lo   = (f16*)alloc((size_t)HD * DD * 2);
  f16* ms_hi   = (f16*)alloc((size_t)MD * HD * 2);   // memory_slots frag-packed hi
  f16* ms_lo   = (f16*)alloc((size_t)MD * HD * 2);
  f16* as_pk   = (f16*)alloc((size_t)MD * MD * 2);   // assoc^T frag-packed
  f16* wd_pk   = (f16*)alloc((size_t)HD * DD * 2);   // W_dec^T frag-packed
  float* query = (float*)alloc((size_t)BD * HD * 4);
  float* scale = (float*)alloc((size_t)BD * 4);
  float* sim   = (float*)alloc((size_t)BD * MD * 4); // reused as act1/act2
  int* idx     = (int*)alloc((size_t)BD * KD * 4);
  float* vals  = (float*)alloc((size_t)BD * KD * 4);
  f16* p_h     = (f16*)alloc((size_t)BD * MD * 2);
  f16* read_h  = (f16*)alloc((size_t)BD * HD * 2);
  (void)ws_size; (void)in_sizes; (void)n_in; (void)out_size;

  dim3 b256(256), b512(512);
  // ---- operand frag-packing ----
  k_pack_T<<<dim3((HD / 16) * (DD / 32) * 64 / 256), b256, 0, stream>>>(W_enc, Wt_hi, Wt_lo, HD, DD);
  k_pack_rows<<<dim3((MD / 16) * (HD / 32) * 64 / 256), b256, 0, stream>>>(mem, ms_hi, ms_lo, MD, HD);
  k_pack_T<<<dim3((MD / 16) * (MD / 32) * 64 / 256), b256, 0, stream>>>(assoc, as_pk, nullptr, MD, MD);
  k_pack_T<<<dim3((DD / 16) * (HD / 32) * 64 / 256), b256, 0, stream>>>(W_dec, wd_pk, nullptr, DD, HD);
  // ---- enc GEMM (split-3, pipelined 256x128) + tanh + mean_s -> query [B,H] ----
  k_gemm2<1, 1><<<dim3((BD * SD / 256) * (HD / 128)), b512, 0, stream>>>(
      x, Wt_hi, Wt_lo, query, b_enc, BD * SD, HD, DD);
  // ---- gate scale per row ----
  k_gate<<<dim3(BD), b256, 0, stream>>>(query, w_curv, b_curv, temp, scale);
  // ---- sim = query @ memory_slots^T (split-3, pipelined) ----
  k_gemm2<1, 0><<<dim3((BD / 256) * (MD / 128)), b512, 0, stream>>>(
      query, ms_hi, ms_lo, sim, nullptr, BD, MD, HD);
  // ---- top-32 ----
  k_topk<<<dim3(BD), b256, 0, stream>>>(sim, scale, idx, vals);
  // ---- two rounds: softmax -> @ assoc ----
  k_softmax<<<dim3(BD), b256, 0, stream>>>(sim, p_h, MD);
  k_gemm2<0, 0><<<dim3((BD / 256) * (MD / 128)), b512, 0, stream>>>(
      p_h, as_pk, nullptr, sim, nullptr, BD, MD, MD);
  k_softmax<<<dim3(BD), b256, 0, stream>>>(sim, p_h, MD);
  k_gemm2<0, 0><<<dim3((BD / 256) * (MD / 128)), b512, 0, stream>>>(
      p_h, as_pk, nullptr, sim, nullptr, BD, MD, MD);
  // ---- combine softmax + weighted gather -> read [B,H] f16 ----
  k_combine<<<dim3(BD), b256, 0, stream>>>(vals, idx, sim, mem, read_h);
  // ---- decode GEMM + tanh + fused broadcast over S -> out [B,S,D] (write-bound; keep 128^2) ----
  k_gemm<0, 3><<<dim3(DD / 128, BD / 128), b256, 0, stream>>>(
      read_h, wd_pk, nullptr, out, b_dec, BD, DD, HD);
}